// Round 11
// baseline (2353.653 us; speedup 1.0000x reference)
//
#include <hip/hip_runtime.h>
#include <hip/hip_bf16.h>

#define DI __device__ __forceinline__

typedef __bf16 bf16x8 __attribute__((ext_vector_type(8)));
typedef __bf16 bf16x4 __attribute__((ext_vector_type(4)));
typedef __bf16 bf16x2 __attribute__((ext_vector_type(2)));
typedef float  f32x4  __attribute__((ext_vector_type(4)));
typedef unsigned long long ull;

static constexpr int Bc = 64, Tc = 256, Ic = 128, Hc = 512, Oc = 64;
static constexpr int TBc = Tc * Bc;                 // 16384
static constexpr size_t THW = (size_t)TBc * Hc;     // 8388608 elems

// ---------- d_out offsets (floats) ----------
static constexpr size_t O_OUT = 0;
static constexpr size_t O_HT  = 4096;
static constexpr size_t O_DW0 = 36864;
static constexpr size_t O_DV0 = 823296;
static constexpr size_t O_DB0 = 1019904;
static constexpr size_t O_ERR = 1021440;

// ---------- ws offsets (bytes) ----------
static constexpr size_t W_SLOT = 1024;     // 9 f32
static constexpr size_t W_DB   = 2048;     // db_raw [3][512] f32 -> ends 8192
static constexpr size_t W_FLG  = 8192;     // barrier epoch flags: 64 slots x 128B -> ends 16384
static constexpr size_t W_ERRW = 16384;    // error [64][64] f32
static constexpr size_t W_PROJ = 32768;    // proj [6][64][512] f32 -> ends 819200
static constexpr size_t W_W1B  = 819200;   // W1 bf16 [512][512] -> ends 1343488
static constexpr size_t W_HX   = 1343488;  // h exchange fp32 [4][8192] (128 KB)
static constexpr size_t W_HRX  = 1474560;  // hr exchange fp32 [4][8192] -> ends 1605632
static constexpr size_t W_XT   = 1605632;  // x^T bf16 [128][TB] -> ends 5799936
static constexpr size_t W_HIST = 5799936;  // r,z,ht,h bf16 [TB][512] each -> ends 72908800
static constexpr size_t W_PB   = 72908800; // xV fp32 (100.6MB) / later P + HpT + RsHpT
static constexpr size_t W_NEED = W_PB + 100663296;   // 173572096

// =========================== helpers ===========================

DI void st32_agent(float* p, float v) {
  __hip_atomic_store((unsigned int*)p, __float_as_uint(v),
                     __ATOMIC_RELAXED, __HIP_MEMORY_SCOPE_AGENT);
}
DI ull ld64_agent(const void* p) {
  return __hip_atomic_load((ull*)p, __ATOMIC_RELAXED, __HIP_MEMORY_SCOPE_AGENT);
}

// Fence-free group barrier via distributed epoch flags (see R3/R6 notes).
DI void group_barrier(int* flags_g, int myslot, int bar, bool& dead) {
  __syncthreads();
  if (threadIdx.x == 0)
    __hip_atomic_store(&flags_g[myslot * 32], bar,
                       __ATOMIC_RELAXED, __HIP_MEMORY_SCOPE_AGENT);
  if (threadIdx.x < 64 && !dead) {
    const int l = threadIdx.x;
    int spins = 0;
    for (;;) {
      int v = bar;
      if (l < 16)
        v = __hip_atomic_load(&flags_g[l * 32],
                              __ATOMIC_RELAXED, __HIP_MEMORY_SCOPE_AGENT);
      if (__all(v >= bar)) break;
      __builtin_amdgcn_s_sleep(1);
      if (++spins > 4000000) { dead = true; break; }   // never hang the bench
    }
  }
  __syncthreads();
}

// hiddens[t-1] with python-negative-index quirk; k = t*64+b
DI float hprev_at(const __bf16* __restrict__ h_h, int k, int col) {
  int t = k >> 6;
  if (t == 1) return 0.f;
  int row = (t == 0) ? (16320 + (k & 63)) : (k - 128);
  return (float)h_h[(size_t)row * 512 + col];
}

// =========================== tiny kernels ===========================

__global__ void ksent(float* p, float v) { p[0] = v; }

// =========================== K1: xV = x@V^T + bias via MFMA =================
// 2-way bf16 split both operands, 3-term Ootomo. g==3 blocks: zero the
// flags/slots/dbr control region (consumed by k2/k5m/k6 -- all later launches).
__global__ __launch_bounds__(256)
void k1_xv(const float* __restrict__ x, const float* __restrict__ V1w,
           const float* __restrict__ V2w, const float* __restrict__ V3w,
           const float* __restrict__ V1b, const float* __restrict__ W2b,
           const float* __restrict__ W3b,
           float* __restrict__ xv1f, float* __restrict__ xv2f, float* __restrict__ xv3f,
           float* __restrict__ wszero)
{
  const int t = blockIdx.x, g = blockIdx.y;
  if (g == 3) {
    if (t < 16) wszero[t * 256 + threadIdx.x] = 0.f;
    return;
  }
  const float* Vg   = (g == 0) ? V1w : (g == 1) ? V2w : V3w;
  const float* bias = (g == 0) ? V1b : (g == 1) ? W2b : W3b;
  float* of = (g == 0) ? xv1f : (g == 1) ? xv2f : xv3f;
  __shared__ __align__(16) __bf16 xs0[64 * 36];
  __shared__ __align__(16) __bf16 xs1[64 * 36];
  __shared__ __align__(16) __bf16 vs0[64 * 36];
  __shared__ __align__(16) __bf16 vs1[64 * 36];
  const int tid = threadIdx.x, lane = tid & 63, wv = tid >> 6;
  const int q = lane >> 4, l15 = lane & 15;
  for (int cb = 0; cb < 8; ++cb) {
    f32x4 acc[4];
    #pragma unroll
    for (int mt = 0; mt < 4; ++mt) acc[mt] = (f32x4){0.f, 0.f, 0.f, 0.f};
    for (int kc = 0; kc < 4; ++kc) {
      __syncthreads();
      #pragma unroll
      for (int e = 0; e < 2; ++e) {
        int idx = tid + e * 256;           // 0..511
        int row = idx >> 3, k4 = (idx & 7) * 4;
        float4 v = *reinterpret_cast<const float4*>(&x[((size_t)row * 256 + t) * 128 + kc * 32 + k4]);
        float fv[4] = {v.x, v.y, v.z, v.w};
        bf16x4 a4, b4;
        #pragma unroll
        for (int j = 0; j < 4; ++j) {
          __bf16 a = (__bf16)fv[j];
          a4[j] = a; b4[j] = (__bf16)(fv[j] - (float)a);
        }
        *reinterpret_cast<bf16x4*>(&xs0[row * 36 + k4]) = a4;
        *reinterpret_cast<bf16x4*>(&xs1[row * 36 + k4]) = b4;
        float4 w = *reinterpret_cast<const float4*>(&Vg[(size_t)(cb * 64 + row) * 128 + kc * 32 + k4]);
        float fw[4] = {w.x, w.y, w.z, w.w};
        #pragma unroll
        for (int j = 0; j < 4; ++j) {
          __bf16 a = (__bf16)fw[j];
          a4[j] = a; b4[j] = (__bf16)(fw[j] - (float)a);
        }
        *reinterpret_cast<bf16x4*>(&vs0[row * 36 + k4]) = a4;
        *reinterpret_cast<bf16x4*>(&vs1[row * 36 + k4]) = b4;
      }
      __syncthreads();
      bf16x8 b0 = *reinterpret_cast<const bf16x8*>(&vs0[(wv * 16 + l15) * 36 + q * 8]);
      bf16x8 b1 = *reinterpret_cast<const bf16x8*>(&vs1[(wv * 16 + l15) * 36 + q * 8]);
      #pragma unroll
      for (int mt = 0; mt < 4; ++mt) {
        bf16x8 a0 = *reinterpret_cast<const bf16x8*>(&xs0[(mt * 16 + l15) * 36 + q * 8]);
        bf16x8 a1 = *reinterpret_cast<const bf16x8*>(&xs1[(mt * 16 + l15) * 36 + q * 8]);
        acc[mt] = __builtin_amdgcn_mfma_f32_16x16x32_bf16(a0, b0, acc[mt], 0, 0, 0);
        acc[mt] = __builtin_amdgcn_mfma_f32_16x16x32_bf16(a1, b0, acc[mt], 0, 0, 0);
        acc[mt] = __builtin_amdgcn_mfma_f32_16x16x32_bf16(a0, b1, acc[mt], 0, 0, 0);
      }
    }
    const int col = cb * 64 + wv * 16 + l15;
    const float bv = bias[col];
    #pragma unroll
    for (int mt = 0; mt < 4; ++mt)
      #pragma unroll
      for (int i = 0; i < 4; ++i) {
        int row = mt * 16 + q * 4 + i;
        of[((size_t)t * 64 + row) * 512 + col] = acc[mt][i] + bv;
      }
  }
}

// =========================== K2 mega-kernel =================================
// blocks 0..63: persistent GRU recurrence (R7's measured ~1570us).
// blocks 64..319: e0_xt; 320..351: W1 cast; 352..415: zero grad accumulators.
__global__ __launch_bounds__(256, 1)
void k2_recur(const float* __restrict__ W1w, const float* __restrict__ W2w,
              const float* __restrict__ W3w,
              const float* __restrict__ xv1, const float* __restrict__ xv2,
              const float* __restrict__ xv3,
              __bf16* __restrict__ r_h, __bf16* __restrict__ z_h,
              __bf16* __restrict__ ht_h, __bf16* __restrict__ h_h,
              float* __restrict__ hx, float* __restrict__ hrx,
              int* __restrict__ flags, float* __restrict__ dout,
              const float* __restrict__ x, __bf16* __restrict__ XT,
              __bf16* __restrict__ W1b)
{
  __shared__ __align__(16) char smem[37376];
  const int tid = threadIdx.x;
  const int bid = blockIdx.x;

  if (bid >= 64) {
    if (bid < 320) {
      const int t = bid - 64;
      __bf16* xs = (__bf16*)smem;          // [64][132]
      #pragma unroll
      for (int e = 0; e < 8; ++e) {
        int idx = tid + e * 256;           // 0..2047
        int b = idx >> 5, c4 = (idx & 31) * 4;
        float4 v = *reinterpret_cast<const float4*>(&x[((size_t)b * 256 + t) * 128 + c4]);
        xs[b * 132 + c4 + 0] = (__bf16)v.x; xs[b * 132 + c4 + 1] = (__bf16)v.y;
        xs[b * 132 + c4 + 2] = (__bf16)v.z; xs[b * 132 + c4 + 3] = (__bf16)v.w;
      }
      __syncthreads();
      #pragma unroll
      for (int e = 0; e < 8; ++e) {
        int idx = tid + e * 256;
        int i = idx >> 4, b4 = (idx & 15) * 4;
        __bf16* d = &XT[(size_t)i * TBc + t * 64 + b4];
        d[0] = xs[(b4 + 0) * 132 + i];
        d[1] = xs[(b4 + 1) * 132 + i];
        d[2] = xs[(b4 + 2) * 132 + i];
        d[3] = xs[(b4 + 3) * 132 + i];
      }
    } else if (bid < 352) {
      for (int i = (bid - 320) * 256 + tid; i < 262144; i += 32 * 256)
        W1b[i] = (__bf16)W1w[i];
    } else {
      float* p = dout + O_DW0;
      for (int i = (bid - 352) * 256 + tid; i < 983040; i += 64 * 256)
        p[i] = 0.f;
    }
    return;
  }

  // ---------------- recurrence (identical to R7) ----------------
  const int g  = bid >> 4;
  const int cw = bid & 15;
  const int lane = tid & 63, wv = tid >> 6;
  const int kh = wv & 1;
  const int ct = wv >> 1;
  const int q  = lane >> 4;
  const int colc = cw * 32 + ct * 16 + (lane & 15);
  const bool owner = (kh == 0);

  __bf16* c0  = (__bf16*)smem;
  __bf16* c1  = (__bf16*)(smem + 16384);
  float*  pbuf = (float*)(smem + 32768);

  bf16x8 w1c[2][8], w2c[2][8], w3c[2][8];
  #pragma unroll
  for (int kk2 = 0; kk2 < 8; ++kk2) {
    const int kb = (kh * 8 + kk2) * 32 + q * 8;
    #pragma unroll
    for (int j = 0; j < 8; ++j) {
      float w = W1w[(size_t)colc * 512 + kb + j];
      __bf16 a = (__bf16)w;
      w1c[0][kk2][j] = a; w1c[1][kk2][j] = (__bf16)(w - (float)a);
      w = W2w[(size_t)colc * 512 + kb + j];
      a = (__bf16)w;
      w2c[0][kk2][j] = a; w2c[1][kk2][j] = (__bf16)(w - (float)a);
      w = W3w[(size_t)colc * 512 + kb + j];
      a = (__bf16)w;
      w3c[0][kk2][j] = a; w3c[1][kk2][j] = (__bf16)(w - (float)a);
    }
  }
  for (int i = tid; i < 8192; i += 256) {
    c0[i] = (__bf16)0.f; c1[i] = (__bf16)0.f;
  }
  __syncthreads();

  float hreg[4] = {0.f, 0.f, 0.f, 0.f};
  float* hx_g  = hx  + g * 8192;
  float* hrx_g = hrx + g * 8192;
  int* flags_g = flags + g * 16 * 32;
  const int fragbase = (colc >> 5) * 512 + (((colc >> 3) & 3) * 16 + q * 4) * 8 + (colc & 7);
  const int pb = (ct * 64 + lane) * 9;

  auto stage = [&](const float* __restrict__ srcf) {
    const ull* src = reinterpret_cast<const ull*>(srcf);
    ull u[16];
    #pragma unroll
    for (int j = 0; j < 16; ++j) u[j] = ld64_agent(src + j * 256 + tid);
    #pragma unroll
    for (int j = 0; j < 16; ++j) {
      float f0 = __uint_as_float((unsigned int)u[j]);
      float f1 = __uint_as_float((unsigned int)(u[j] >> 32));
      __bf16 a0 = (__bf16)f0; __bf16 b0 = (__bf16)(f0 - (float)a0);
      __bf16 a1 = (__bf16)f1; __bf16 b1 = (__bf16)(f1 - (float)a1);
      int o = (j * 256 + tid) * 2;
      bf16x2 v0; v0[0] = a0; v0[1] = a1;
      bf16x2 v1; v1[0] = b0; v1[1] = b1;
      *reinterpret_cast<bf16x2*>(&c0[o]) = v0;
      *reinterpret_cast<bf16x2*>(&c1[o]) = v1;
    }
  };

  bool dead = false;
  int bar = 0;
  #pragma unroll 1
  for (int t = 0; t < Tc; ++t) {
    const size_t rowb = ((size_t)t * 64 + g * 16 + q * 4) * 512 + colc;
    float xv1v[4], xv2v[4], xv3v[4];
    if (owner) {
      #pragma unroll
      for (int i = 0; i < 4; ++i) {
        size_t o = rowb + (size_t)i * 512;
        xv1v[i] = xv1[o]; xv2v[i] = xv2[o]; xv3v[i] = xv3[o];
      }
    }
    f32x4 a2 = {0.f,0.f,0.f,0.f}, a3 = {0.f,0.f,0.f,0.f};
    #pragma unroll
    for (int kk2 = 0; kk2 < 8; ++kk2) {
      const int idx = (kh * 8 + kk2) * 512 + lane * 8;
      bf16x8 h0 = *reinterpret_cast<const bf16x8*>(&c0[idx]);
      bf16x8 h1 = *reinterpret_cast<const bf16x8*>(&c1[idx]);
      a2 = __builtin_amdgcn_mfma_f32_16x16x32_bf16(h0, w2c[0][kk2], a2, 0, 0, 0);
      a2 = __builtin_amdgcn_mfma_f32_16x16x32_bf16(h1, w2c[0][kk2], a2, 0, 0, 0);
      a2 = __builtin_amdgcn_mfma_f32_16x16x32_bf16(h0, w2c[1][kk2], a2, 0, 0, 0);
      a3 = __builtin_amdgcn_mfma_f32_16x16x32_bf16(h0, w3c[0][kk2], a3, 0, 0, 0);
      a3 = __builtin_amdgcn_mfma_f32_16x16x32_bf16(h1, w3c[0][kk2], a3, 0, 0, 0);
      a3 = __builtin_amdgcn_mfma_f32_16x16x32_bf16(h0, w3c[1][kk2], a3, 0, 0, 0);
    }
    if (!owner) {
      #pragma unroll
      for (int i = 0; i < 4; ++i) { pbuf[pb + i] = a2[i]; pbuf[pb + 4 + i] = a3[i]; }
    }
    __syncthreads();
    float zz[4], rr4[4];
    if (owner) {
      #pragma unroll
      for (int i = 0; i < 4; ++i) {
        float s2 = a2[i] + pbuf[pb + i]     + xv2v[i];
        float s3 = a3[i] + pbuf[pb + 4 + i] + xv3v[i];
        zz[i]  = 1.f / (1.f + expf(-s2));
        rr4[i] = 1.f / (1.f + expf(-s3));
        st32_agent(&hrx_g[fragbase + i * 8], hreg[i] * rr4[i]);
      }
    }
    ++bar; group_barrier(flags_g, cw, bar, dead);
    if (owner) {
      #pragma unroll
      for (int i = 0; i < 4; ++i) {
        z_h[rowb + (size_t)i * 512] = (__bf16)zz[i];
        r_h[rowb + (size_t)i * 512] = (__bf16)rr4[i];
      }
    }
    stage(hrx_g);
    __syncthreads();
    f32x4 a1 = {0.f,0.f,0.f,0.f};
    #pragma unroll
    for (int kk2 = 0; kk2 < 8; ++kk2) {
      const int idx = (kh * 8 + kk2) * 512 + lane * 8;
      bf16x8 h0 = *reinterpret_cast<const bf16x8*>(&c0[idx]);
      bf16x8 h1 = *reinterpret_cast<const bf16x8*>(&c1[idx]);
      a1 = __builtin_amdgcn_mfma_f32_16x16x32_bf16(h0, w1c[0][kk2], a1, 0, 0, 0);
      a1 = __builtin_amdgcn_mfma_f32_16x16x32_bf16(h1, w1c[0][kk2], a1, 0, 0, 0);
      a1 = __builtin_amdgcn_mfma_f32_16x16x32_bf16(h0, w1c[1][kk2], a1, 0, 0, 0);
    }
    if (!owner) {
      #pragma unroll
      for (int i = 0; i < 4; ++i) pbuf[pb + i] = a1[i];
    }
    __syncthreads();
    float htv[4];
    if (owner) {
      #pragma unroll
      for (int i = 0; i < 4; ++i) {
        float pre = a1[i] + pbuf[pb + i] + xv1v[i];
        float ht = tanhf(pre);
        float hn = zz[i] * (hreg[i] - ht) + ht;
        htv[i] = ht;
        hreg[i] = hn;
        st32_agent(&hx_g[fragbase + i * 8], hn);
      }
    }
    ++bar; group_barrier(flags_g, cw, bar, dead);
    if (owner) {
      #pragma unroll
      for (int i = 0; i < 4; ++i) {
        ht_h[rowb + (size_t)i * 512] = (__bf16)htv[i];
        h_h[rowb + (size_t)i * 512]  = (__bf16)hreg[i];
      }
    }
    if (t + 1 < Tc) stage(hx_g);
    __syncthreads();
  }
  if (owner) {
    #pragma unroll
    for (int i = 0; i < 4; ++i) {
      int b = g * 16 + q * 4 + i;
      dout[O_HT + (size_t)b * 512 + colc] = hreg[i];
    }
  }
}

// =========================== K3A: logits/softmax/error (16 blocks) ==========
__global__ __launch_bounds__(256)
void k3a_soft(const float* __restrict__ Woutw, const float* __restrict__ Woutb,
              const int* __restrict__ y, float* __restrict__ dout,
              float* __restrict__ errw)
{
  const int b = blockIdx.x * 4 + (threadIdx.x >> 6);
  const int o = threadIdx.x & 63;
  const float* hrow = dout + O_HT + (size_t)b * 512;
  float sv = Woutb[o];
  for (int k = 0; k < 512; ++k) sv += hrow[k] * Woutw[(size_t)o * 512 + k];
  float mx = sv;
  for (int off = 32; off; off >>= 1) mx = fmaxf(mx, __shfl_xor(mx, off, 64));
  float e = expf(sv - mx);
  float sum = e;
  for (int off = 32; off; off >>= 1) sum += __shfl_xor(sum, off, 64);
  float outp = e / sum;
  float errv = outp - ((y[b] == o) ? 1.f : 0.f);
  dout[O_OUT + b * 64 + o] = outp;
  dout[O_ERR + b * 64 + o] = errv;
  errw[b * 64 + o] = errv;
}

// =========================== K3b: 6 DFA projections ===========================
__global__ __launch_bounds__(256)
void k3b_proj(const float* __restrict__ err,
              const float* b0, const float* b1, const float* b2,
              const float* b3, const float* b4, const float* b5,
              float* __restrict__ proj)
{
  const int p = blockIdx.y;
  const int hb = blockIdx.x * 64;
  const float* BX = (p==0)?b0:(p==1)?b1:(p==2)?b2:(p==3)?b3:(p==4)?b4:b5;
  __shared__ float es[64 * 64];
  __shared__ float bs[64 * 65];
  for (int i = threadIdx.x; i < 4096; i += 256) es[i] = err[i];
  for (int i = threadIdx.x; i < 4096; i += 256) {
    int o = i >> 6, hh = i & 63;
    bs[o * 65 + hh] = BX[(size_t)o * 512 + hb + hh];
  }
  __syncthreads();
  for (int e = 0; e < 16; ++e) {
    int idx = threadIdx.x + e * 256;
    int b = idx >> 6, hh = idx & 63;
    float s = 0.f;
    for (int o = 0; o < 64; ++o) s += es[b * 64 + o] * bs[o * 65 + hh];
    proj[(size_t)p * 32768 + b * 512 + hb + hh] = s;
  }
}

// =========================== K4E: plane-pair P GEMM + e1t merged ============
// blocks 0..1023: P GEMM (pp = bid>>9: pp=0 planes {0:AV,1:AW}, pp=1 {2:HV,
// 3:HW}); blocks 1024..3071: e1t HpT/RsHpT transposes (consumed by k5m, reads
// only k2 outputs -- co-runs on CUs the GEMM leaves under-fed).
__global__ __launch_bounds__(256)
void k4e(const __bf16* __restrict__ z_h, const __bf16* __restrict__ ht_h,
         const __bf16* __restrict__ r_h, const __bf16* __restrict__ h_h,
         const float* __restrict__ proj, const __bf16* __restrict__ W1b,
         __bf16* __restrict__ P, __bf16* __restrict__ HpT,
         __bf16* __restrict__ RsHpT)
{
  __shared__ __align__(16) char smem[30720];
  const int bid = blockIdx.x, tid = threadIdx.x;
  if (bid >= 1024) {
    // ---- e1t ----
    const int b2 = bid - 1024;
    const int t = b2 >> 3, hb = (b2 & 7) * 64;
    __bf16* tr = (__bf16*)smem;     // [64][68]
    float hpv[16], rv[16];
    #pragma unroll
    for (int e = 0; e < 16; ++e) {
      int idx = tid + e * 256;
      int b = idx >> 6, hl = idx & 63;
      hpv[e] = hprev_at(h_h, t * 64 + b, hb + hl);
      rv[e]  = (float)r_h[((size_t)t * 64 + b) * 512 + hb + hl];
    }
    for (int rnd = 0; rnd < 2; ++rnd) {
      __syncthreads();
      #pragma unroll
      for (int e = 0; e < 16; ++e) {
        int idx = tid + e * 256;
        int b = idx >> 6, hl = idx & 63;
        tr[b * 68 + hl] = (__bf16)(rnd == 0 ? hpv[e] : rv[e] * hpv[e]);
      }
      __syncthreads();
      __bf16* dst = (rnd == 0) ? HpT : RsHpT;
      #pragma unroll
      for (int e = 0; e < 16; ++e) {
        int idx = tid + e * 256;
        int hl2 = idx >> 6, b2i = idx & 63;
        dst[(size_t)(hb + hl2) * TBc + t * 64 + b2i] = tr[b2i * 68 + hl2];
      }
    }
    return;
  }
  // ---- plane-pair P GEMM ----
  const int pp = bid >> 9;
  const int rem = bid & 511;
  const int krow0 = (rem & 127) * 128;
  const int n0 = (rem >> 7) * 128;
  const float* prA = proj + (size_t)(pp == 0 ? 5 : 1) * 32768;
  const float* prB = proj + (size_t)(pp == 0 ? 4 : 0) * 32768;
  const int lane = tid & 63, wv = tid >> 6, q = lane >> 4;
  const int wm = (wv & 1) * 64, wn = (wv >> 1) * 64;
  __bf16* Al0 = (__bf16*)smem;                 // [128][40]
  __bf16* Al1 = (__bf16*)(smem + 10240);
  __bf16* Bl  = (__bf16*)(smem + 20480);
  f32x4 acc0[4][4] = {}, acc1[4][4] = {};
  for (int kt = 0; kt < 16; ++kt) {
    const int h0 = kt * 32;
    __syncthreads();
    #pragma unroll
    for (int e = 0; e < 4; ++e) {
      int idx = tid + e * 256;                 // 0..1023
      int row = idx >> 3, h4 = (idx & 7) * 4;
      int kg = krow0 + row;
      bf16x4 zz = *reinterpret_cast<const bf16x4*>(&z_h[(size_t)kg * 512 + h0 + h4]);
      float4 pva = *reinterpret_cast<const float4*>(&prA[(size_t)(kg & 63) * 512 + h0 + h4]);
      float4 pvb = *reinterpret_cast<const float4*>(&prB[(size_t)(kg & 63) * 512 + h0 + h4]);
      float pA[4] = {pva.x, pva.y, pva.z, pva.w};
      float pB[4] = {pvb.x, pvb.y, pvb.z, pvb.w};
      bf16x4 gv0, gv1;
      if (pp == 0) {
        bf16x4 tt = *reinterpret_cast<const bf16x4*>(&ht_h[(size_t)kg * 512 + h0 + h4]);
        #pragma unroll
        for (int j = 0; j < 4; ++j) {
          float sz = 1.f - (float)zz[j];
          float h = (float)tt[j];
          float f = sz * (1.f - h * h);
          gv0[j] = (__bf16)(pA[j] * f);
          gv1[j] = (__bf16)(pB[j] * f);
        }
      } else {
        #pragma unroll
        for (int j = 0; j < 4; ++j) {
          float sz = 1.f - (float)zz[j];
          gv0[j] = (__bf16)(pA[j] * sz);
          gv1[j] = (__bf16)(pB[j] * sz);
        }
      }
      *reinterpret_cast<bf16x4*>(&Al0[row * 40 + h4]) = gv0;
      *reinterpret_cast<bf16x4*>(&Al1[row * 40 + h4]) = gv1;
      bf16x4 wv4 = *reinterpret_cast<const bf16x4*>(&W1b[(size_t)(n0 + row) * 512 + h0 + h4]);
      *reinterpret_cast<bf16x4*>(&Bl[row * 40 + h4]) = wv4;
    }
    __syncthreads();
    bf16x8 af0[4], af1[4], bfv[4];
    #pragma unroll
    for (int mi = 0; mi < 4; ++mi) {
      af0[mi] = *reinterpret_cast<const bf16x8*>(&Al0[(wm + mi * 16 + (lane & 15)) * 40 + q * 8]);
      af1[mi] = *reinterpret_cast<const bf16x8*>(&Al1[(wm + mi * 16 + (lane & 15)) * 40 + q * 8]);
    }
    #pragma unroll
    for (int ni = 0; ni < 4; ++ni)
      bfv[ni] = *reinterpret_cast<const bf16x8*>(&Bl[(wn + ni * 16 + (lane & 15)) * 40 + q * 8]);
    #pragma unroll
    for (int mi = 0; mi < 4; ++mi)
      #pragma unroll
      for (int ni = 0; ni < 4; ++ni) {
        acc0[mi][ni] = __builtin_amdgcn_mfma_f32_16x16x32_bf16(af0[mi], bfv[ni], acc0[mi][ni], 0, 0, 0);
        acc1[mi][ni] = __builtin_amdgcn_mfma_f32_16x16x32_bf16(af1[mi], bfv[ni], acc1[mi][ni], 0, 0, 0);
      }
  }
  __bf16* Pp0 = P + (size_t)(2 * pp) * THW;
  __bf16* Pp1 = P + (size_t)(2 * pp + 1) * THW;
  #pragma unroll
  for (int mi = 0; mi < 4; ++mi) {
    const int kg = krow0 + wm + mi * 16 + q * 4;
    const int tt = kg >> 6;
    #pragma unroll
    for (int ni = 0; ni < 4; ++ni) {
      const int n = n0 + wn + ni * 16 + (lane & 15);
      union { __bf16 b[4]; uint2 u; } pk0, pk1;
      #pragma unroll
      for (int i = 0; i < 4; ++i) {
        float mul;
        if (pp == 0) {
          float r = (float)r_h[(size_t)(kg + i) * 512 + n];
          float hp = 0.f;
          if (tt != 1) {
            int kr = (tt == 0) ? (16320 + (kg & 63) + i) : (kg + i - 128);
            hp = (float)h_h[(size_t)kr * 512 + n];
          }
          mul = hp * r * (1.f - r);
        } else {
          float h = (float)ht_h[(size_t)(kg + i) * 512 + n];
          mul = 1.f - h * h;
        }
        pk0.b[i] = (__bf16)(acc0[mi][ni][i] * mul);
        pk1.b[i] = (__bf16)(acc1[mi][ni][i] * mul);
      }
      *reinterpret_cast<uint2*>(&Pp0[(size_t)n * TBc + kg]) = pk0.u;
      *reinterpret_cast<uint2*>(&Pp1[(size_t)n * TBc + kg]) = pk1.u;
    }
  }
}

// =========================== K5M: grad GEMMs + dbP + dbzg merged ============
// klen=1024 (split-k 16 -- R9's measured-better mapping). blocks 0..767: dW
// jobs; 768..959: dV jobs; 960..1983: k_dbP; 1984..2111: k_dbzg (reads
// proj[3], ready post-k3b).
__global__ __launch_bounds__(256)
void k5m(const __bf16* __restrict__ P, const __bf16* __restrict__ RsHpT,
         const __bf16* __restrict__ HpT, const __bf16* __restrict__ XT,
         const __bf16* __restrict__ r_h, const __bf16* __restrict__ ht_h,
         const __bf16* __restrict__ h_h, const float* __restrict__ proj,
         float* __restrict__ dout, float* __restrict__ db, float scale)
{
  __shared__ __align__(16) char smem[36864];
  const int bid = blockIdx.x, tid = threadIdx.x;
  if (bid >= 1984) {
    // ---- k_dbzg: db1 partials ----
    const int b2 = bid - 1984;
    const int hb = (b2 & 7) * 64;
    const int col = hb + (tid & 63);
    const int part = tid >> 6;
    const int kb = (b2 >> 3) * 1024;
    float sum = 0.f;
    for (int k = kb + part; k < kb + 1024; k += 4) {
      float hs = (float)ht_h[(size_t)k * 512 + col];
      float r  = (float)r_h[(size_t)k * 512 + col];
      float hp = hprev_at(h_h, k, col);
      float pv = proj[3 * 32768 + (size_t)(k & 63) * 512 + col];
      sum += (hp - hs) * r * (1.f - r) * pv;
    }
    float (*sred)[64] = (float(*)[64])smem;
    sred[part][tid & 63] = sum;
    __syncthreads();
    if (tid < 64)
      atomicAdd(&db[512 + hb + tid],
                (sred[0][tid] + sred[1][tid] + sred[2][tid] + sred[3][tid]) * (1.f / 64.f));
    return;
  }
  if (bid >= 960) {
    // ---- k_dbP ----
    const int idx = bid - 960;
    const size_t plane = ((idx >> 9) == 0) ? 2 : 0;
    const int dbo = ((idx >> 9) == 0) ? 0 : 1024;
    const int xrow = idx & 511;
    const __bf16* row = P + plane * THW + (size_t)xrow * TBc;
    float sv = 0.f;
    for (int i = tid; i < TBc; i += 256) sv += (float)row[i];
    for (int off = 32; off; off >>= 1) sv += __shfl_xor(sv, off, 64);
    float* red = (float*)smem;
    if ((tid & 63) == 0) red[tid >> 6] = sv;
    __syncthreads();
    if (tid == 0)
      atomicAdd(&db[dbo + xrow], (red[0] + red[1] + red[2] + red[3]) * (1.f / 64.f));
    return;
  }
  const __bf16* Ap; int amode; const __bf16* Bp; const float* projA;
  float* out; int N; int m0i, n0i, zi;
  if (bid < 768) {
    int job = bid >> 8, wb = bid & 255;
    m0i = wb & 3; n0i = (wb >> 2) & 3; zi = wb >> 4;   // zi 0..15
    N = 512;
    out = dout + O_DW0 + (size_t)job * 262144;
    if (job == 0)      { Ap = P + 3 * THW; amode = 0; Bp = RsHpT; projA = proj; }
    else if (job == 1) { Ap = nullptr;     amode = 1; Bp = HpT;   projA = proj + 2 * 32768; }
    else               { Ap = P + 1 * THW; amode = 0; Bp = HpT;   projA = proj; }
  } else {
    int b2 = bid - 768; int job = b2 >> 6, wb = b2 & 63;
    m0i = wb & 3; n0i = 0; zi = wb >> 2;               // zi 0..15
    N = 128;
    out = dout + O_DV0 + (size_t)job * 65536;
    if (job == 0)      { Ap = P + 2 * THW; amode = 0; Bp = XT; projA = proj; }
    else if (job == 1) { Ap = nullptr;     amode = 1; Bp = XT; projA = proj + 3 * 32768; }
    else               { Ap = P + 0 * THW; amode = 0; Bp = XT; projA = proj; }
  }
  const int m0 = m0i * 128;
  const int n0 = n0i * 128;
  const int klen = 1024;
  const int lane = tid & 63, wv = tid >> 6, q = lane >> 4;
  const int wm = (wv & 1) * 64, wn = (wv >> 1) * 64;
  __bf16* Al = (__bf16*)smem;                 // [128][72]
  __bf16* Bl = (__bf16*)(smem + 18432);       // [128][72]
  f32x4 acc[4][4] = {};
  const int iters = klen >> 6;
  for (int kt = 0; kt < iters; ++kt) {
    const int kk0 = zi * klen + kt * 64;
    __syncthreads();
    #pragma unroll
    for (int e = 0; e < 8; ++e) {
      int idx = tid + e * 256;              // 0..2047
      int row = idx >> 4, c4 = (idx & 15) * 4;
      bf16x4 bv = *reinterpret_cast<const bf16x4*>(&Bp[(size_t)(n0 + row) * TBc + kk0 + c4]);
      *reinterpret_cast<bf16x4*>(&Bl[row * 72 + c4]) = bv;
    }
    if (amode == 0) {
      #pragma unroll
      for (int e = 0; e < 8; ++e) {
        int idx = tid + e * 256;
        int row = idx >> 4, c4 = (idx & 15) * 4;
        bf16x4 av = *reinterpret_cast<const bf16x4*>(&Ap[(size_t)(m0 + row) * TBc + kk0 + c4]);
        *reinterpret_cast<bf16x4*>(&Al[row * 72 + c4]) = av;
      }
    } else {
      #pragma unroll
      for (int e = 0; e < 8; ++e) {
        int idx = tid + e * 256;
        int kk = idx >> 5;                  // 0..63 local k row
        int m4 = (idx & 31) * 4;
        int kg = kk0 + kk;
        int tt = kg >> 6;
        bf16x4 hs = *reinterpret_cast<const bf16x4*>(&ht_h[(size_t)kg * 512 + m0 + m4]);
        bf16x4 rv = *reinterpret_cast<const bf16x4*>(&r_h[(size_t)kg * 512 + m0 + m4]);
        float4 pv = *reinterpret_cast<const float4*>(&projA[(size_t)(kg & 63) * 512 + m0 + m4]);
        float pvv[4] = {pv.x, pv.y, pv.z, pv.w};
        float hpf[4] = {0.f, 0.f, 0.f, 0.f};
        if (tt != 1) {
          int kr = (tt == 0) ? (16320 + (kg & 63)) : (kg - 128);
          bf16x4 hp = *reinterpret_cast<const bf16x4*>(&h_h[(size_t)kr * 512 + m0 + m4]);
          #pragma unroll
          for (int j = 0; j < 4; ++j) hpf[j] = (float)hp[j];
        }
        #pragma unroll
        for (int j = 0; j < 4; ++j) {
          float r = (float)rv[j];
          float zg = (hpf[j] - (float)hs[j]) * r * (1.f - r) * pvv[j];
          Al[(m4 + j) * 72 + kk] = (__bf16)zg;
        }
      }
    }
    __syncthreads();
    #pragma unroll
    for (int ks = 0; ks < 2; ++ks) {
      bf16x8 af[4], bfv[4];
      #pragma unroll
      for (int mi = 0; mi < 4; ++mi)
        af[mi] = *reinterpret_cast<const bf16x8*>(&Al[(wm + mi * 16 + (lane & 15)) * 72 + ks * 32 + q * 8]);
      #pragma unroll
      for (int ni = 0; ni < 4; ++ni)
        bfv[ni] = *reinterpret_cast<const bf16x8*>(&Bl[(wn + ni * 16 + (lane & 15)) * 72 + ks * 32 + q * 8]);
      #pragma unroll
      for (int mi = 0; mi < 4; ++mi)
        #pragma unroll
        for (int ni = 0; ni < 4; ++ni)
          acc[mi][ni] = __builtin_amdgcn_mfma_f32_16x16x32_bf16(af[mi], bfv[ni], acc[mi][ni], 0, 0, 0);
    }
  }
  #pragma unroll
  for (int mi = 0; mi < 4; ++mi) {
    const int m = m0 + wm + mi * 16 + q * 4;
    #pragma unroll
    for (int ni = 0; ni < 4; ++ni) {
      const int n = n0 + wn + ni * 16 + (lane & 15);
      #pragma unroll
      for (int i = 0; i < 4; ++i)
        atomicAdd(&out[(size_t)(m + i) * N + n], acc[mi][ni][i] * scale);
    }
  }
}

// =========================== K6: norm + clip (grads live in d_out) ===========================
__global__ void k6a_sumsq(const float* __restrict__ dout, const float* __restrict__ db,
                          float* __restrict__ slots)
{
  const int yy = blockIdx.y;
  const float* src; int count;
  if (yy < 3)      { src = dout + O_DW0 + (size_t)yy * 262144; count = 262144; }
  else if (yy < 6) { src = dout + O_DV0 + (size_t)(yy - 3) * 65536; count = 65536; }
  else             { src = db + (size_t)(yy - 6) * 512; count = 512; }
  int start = blockIdx.x * 4096;
  if (start >= count) return;
  int end = min(start + 4096, count);
  float sp = 0.f;
  for (int i = start + threadIdx.x; i < end; i += 256) { float v = src[i]; sp += v * v; }
  for (int off = 32; off; off >>= 1) sp += __shfl_xor(sp, off, 64);
  __shared__ float red[4];
  if ((threadIdx.x & 63) == 0) red[threadIdx.x >> 6] = sp;
  __syncthreads();
  if (threadIdx.x == 0) atomicAdd(&slots[yy], red[0] + red[1] + red[2] + red[3]);
}

__global__ void k6b_write(const float* __restrict__ db,
                          const float* __restrict__ slots, float* __restrict__ dout)
{
  const int yy = blockIdx.y;
  const float* src; int count; size_t oo;
  if (yy < 3)      { oo = O_DW0 + (size_t)yy * 262144; src = dout + oo; count = 262144; }
  else if (yy < 6) { oo = O_DV0 + (size_t)(yy - 3) * 65536; src = dout + oo; count = 65536; }
  else             { oo = O_DB0 + (size_t)(yy - 6) * 512; src = db + (size_t)(yy - 6) * 512; count = 512; }
  int start = blockIdx.x * 4096;
  if (start >= count) return;
  int end = min(start + 4096, count);
  float inv = 1.f / sqrtf(slots[yy]);
  for (int i = start + threadIdx.x; i < end; i += 256) {
    float v = src[i] * inv;
    dout[oo + i] = fminf(fmaxf(v, -5.f), 5.f);
  }
}

// =========================== launch ===========================
extern "C" void kernel_launch(void* const* d_in, const int* in_sizes, int n_in,
                              void* d_out, int out_size, void* d_ws, size_t ws_size,
                              hipStream_t stream)
{
  const float* x     = (const float*)d_in[0];
  const int*   y     = (const int*)d_in[1];
  const float* W1w   = (const float*)d_in[2];
  const float* V1w   = (const float*)d_in[3];
  const float* V1b   = (const float*)d_in[4];
  const float* W2w   = (const float*)d_in[5];
  const float* W2b   = (const float*)d_in[6];
  const float* V2w   = (const float*)d_in[7];
  const float* W3w   = (const float*)d_in[8];
  const float* W3b   = (const float*)d_in[9];
  const float* V3w   = (const float*)d_in[10];
  const float* Woutw = (const float*)d_in[11];
  const float* Woutb = (const float*)d_in[12];
  const float* BW1   = (const float*)d_in[13];
  const float* BV1   = (const float*)d_in[14];
  const float* BW2   = (const float*)d_in[15];
  const float* BV2   = (const float*)d_in[16];
  const float* BW3   = (const float*)d_in[17];
  const float* BV3   = (const float*)d_in[18];
  float* dout = (float*)d_out;
  char* ws = (char*)d_ws;

  if (ws_size < W_NEED) { ksent<<<1, 1, 0, stream>>>(dout, (float)ws_size); return; }

  float*  slots = (float*)(ws + W_SLOT);
  float*  dbr   = (float*)(ws + W_DB);
  int*    flg   = (int*)(ws + W_FLG);
  float*  errw  = (float*)(ws + W_ERRW);
  float*  proj  = (float*)(ws + W_PROJ);
  __bf16* W1b   = (__bf16*)(ws + W_W1B);
  float*  hx    = (float*)(ws + W_HX);
  float*  hrx   = (float*)(ws + W_HRX);
  __bf16* XT    = (__bf16*)(ws + W_XT);
  __bf16* r_h   = (__bf16*)(ws + W_HIST);
  __bf16* z_h   = (__bf16*)(ws + W_HIST + 16777216);
  __bf16* ht_h  = (__bf16*)(ws + W_HIST + 33554432);
  __bf16* h_h   = (__bf16*)(ws + W_HIST + 50331648);
  char*   PB    = ws + W_PB;

  // xV fp32 (dead after k2) aliases P/HpT/RsHpT (live after k2)
  float* xv1 = (float*)PB;
  float* xv2 = (float*)(PB + 33554432);
  float* xv3 = (float*)(PB + 67108864);
  __bf16* P     = (__bf16*)PB;                     // 4 x [512][TB] bf16 = 67.1 MB
  __bf16* HpT   = (__bf16*)(PB + 67108864);
  __bf16* RsHpT = (__bf16*)(PB + 83886080);

  // k1 (g<3): xV GEMMs; g==3: zero slots+dbr+flags control region
  k1_xv<<<dim3(256, 4), 256, 0, stream>>>(x, V1w, V2w, V3w, V1b, W2b, W3b,
                                          xv1, xv2, xv3, (float*)ws);
  // mega kernel: recurrence (blocks 0..63) + e0_xt (64..319) + W1 cast
  // (320..351) + grad-accumulator zero (352..415) on otherwise-idle CUs
  k2_recur<<<416, 256, 0, stream>>>(W1w, W2w, W3w, xv1, xv2, xv3,
                                    r_h, z_h, ht_h, h_h, hx, hrx, flg, dout,
                                    x, XT, W1b);
  k3a_soft<<<16, 256, 0, stream>>>(Woutw, Woutb, y, dout, errw);
  k3b_proj<<<dim3(8, 6), 256, 0, stream>>>(errw, BW1, BV1, BW2, BV2, BW3, BV3, proj);
  // merged: plane-pair P GEMM (0..1023) + e1t (1024..3071)
  k4e<<<3072, 256, 0, stream>>>(z_h, ht_h, r_h, h_h, proj, W1b, P, HpT, RsHpT);
  const float sc = 1.f / 64.f;
  // merged: dW/dV grad GEMMs klen=1024 (0..959) + k_dbP (960..1983) + k_dbzg (1984..2111)
  k5m<<<2112, 256, 0, stream>>>(P, RsHpT, HpT, XT, r_h, ht_h, h_h, proj, dout, dbr, sc);
  k6a_sumsq<<<dim3(64, 9), 256, 0, stream>>>(dout, dbr, slots);
  k6b_write<<<dim3(64, 9), 256, 0, stream>>>(dbr, slots, dout);
}

// Round 12
// 2293.875 us; speedup vs baseline: 1.0261x; 1.0261x over previous
//
#include <hip/hip_runtime.h>
#include <hip/hip_bf16.h>

#define DI __device__ __forceinline__

typedef __bf16 bf16x8 __attribute__((ext_vector_type(8)));
typedef __bf16 bf16x4 __attribute__((ext_vector_type(4)));
typedef __bf16 bf16x2 __attribute__((ext_vector_type(2)));
typedef float  f32x4  __attribute__((ext_vector_type(4)));
typedef unsigned long long ull;

static constexpr int Bc = 64, Tc = 256, Ic = 128, Hc = 512, Oc = 64;
static constexpr int TBc = Tc * Bc;                 // 16384
static constexpr size_t THW = (size_t)TBc * Hc;     // 8388608 elems

// ---------- d_out offsets (floats) ----------
static constexpr size_t O_OUT = 0;
static constexpr size_t O_HT  = 4096;
static constexpr size_t O_DW0 = 36864;
static constexpr size_t O_DV0 = 823296;
static constexpr size_t O_DB0 = 1019904;
static constexpr size_t O_ERR = 1021440;

// ---------- ws offsets (bytes) ----------
static constexpr size_t W_SLOT = 1024;     // 9 f32
static constexpr size_t W_DB   = 2048;     // db_raw [3][512] f32 -> ends 8192
static constexpr size_t W_FLG  = 8192;     // barrier epoch flags: 64 slots x 128B -> ends 16384
static constexpr size_t W_ERRW = 16384;    // error [64][64] f32
static constexpr size_t W_PROJ = 32768;    // proj [6][64][512] f32 -> ends 819200
static constexpr size_t W_W1B  = 819200;   // W1 bf16 [512][512] -> ends 1343488
static constexpr size_t W_HX   = 1343488;  // h exchange fp32 [4][8192] (128 KB)
static constexpr size_t W_HRX  = 1474560;  // hr exchange fp32 [4][8192] -> ends 1605632
static constexpr size_t W_XT   = 1605632;  // x^T bf16 [128][TB] -> ends 5799936
static constexpr size_t W_HIST = 5799936;  // r,z,ht,h bf16 [TB][512] each -> ends 72908800
static constexpr size_t W_PB   = 72908800; // xV fp32 (100.6MB) / later P + HpT + RsHpT
static constexpr size_t W_NEED = W_PB + 100663296;   // 173572096

// =========================== helpers ===========================

DI void st32_agent(float* p, float v) {
  __hip_atomic_store((unsigned int*)p, __float_as_uint(v),
                     __ATOMIC_RELAXED, __HIP_MEMORY_SCOPE_AGENT);
}
DI ull ld64_agent(const void* p) {
  return __hip_atomic_load((ull*)p, __ATOMIC_RELAXED, __HIP_MEMORY_SCOPE_AGENT);
}

// Fence-free group barrier via distributed epoch flags (see R3/R6 notes).
DI void group_barrier(int* flags_g, int myslot, int bar, bool& dead) {
  __syncthreads();
  if (threadIdx.x == 0)
    __hip_atomic_store(&flags_g[myslot * 32], bar,
                       __ATOMIC_RELAXED, __HIP_MEMORY_SCOPE_AGENT);
  if (threadIdx.x < 64 && !dead) {
    const int l = threadIdx.x;
    int spins = 0;
    for (;;) {
      int v = bar;
      if (l < 16)
        v = __hip_atomic_load(&flags_g[l * 32],
                              __ATOMIC_RELAXED, __HIP_MEMORY_SCOPE_AGENT);
      if (__all(v >= bar)) break;
      __builtin_amdgcn_s_sleep(1);
      if (++spins > 4000000) { dead = true; break; }   // never hang the bench
    }
  }
  __syncthreads();
}

// hiddens[t-1] with python-negative-index quirk; k = t*64+b
DI float hprev_at(const __bf16* __restrict__ h_h, int k, int col) {
  int t = k >> 6;
  if (t == 1) return 0.f;
  int row = (t == 0) ? (16320 + (k & 63)) : (k - 128);
  return (float)h_h[(size_t)row * 512 + col];
}

// =========================== tiny kernels ===========================

__global__ void kzero(float* __restrict__ p, int n) {
  int i = blockIdx.x * 256 + threadIdx.x;
  if (i < n) p[i] = 0.f;
}
__global__ void ksent(float* p, float v) { p[0] = v; }

// =========================== K1: xV = x@V^T + bias via MFMA =================
// 2-way bf16 split both operands, 3-term Ootomo (error ~1e-4 on
// pre-activations, negligible vs the 2e-3 recurrence absmax).
__global__ __launch_bounds__(256)
void k1_xv(const float* __restrict__ x, const float* __restrict__ V1w,
           const float* __restrict__ V2w, const float* __restrict__ V3w,
           const float* __restrict__ V1b, const float* __restrict__ W2b,
           const float* __restrict__ W3b,
           float* __restrict__ xv1f, float* __restrict__ xv2f, float* __restrict__ xv3f)
{
  const int t = blockIdx.x, g = blockIdx.y;
  const float* Vg   = (g == 0) ? V1w : (g == 1) ? V2w : V3w;
  const float* bias = (g == 0) ? V1b : (g == 1) ? W2b : W3b;
  float* of = (g == 0) ? xv1f : (g == 1) ? xv2f : xv3f;
  __shared__ __align__(16) __bf16 xs0[64 * 36];
  __shared__ __align__(16) __bf16 xs1[64 * 36];
  __shared__ __align__(16) __bf16 vs0[64 * 36];
  __shared__ __align__(16) __bf16 vs1[64 * 36];
  const int tid = threadIdx.x, lane = tid & 63, wv = tid >> 6;
  const int q = lane >> 4, l15 = lane & 15;
  for (int cb = 0; cb < 8; ++cb) {
    f32x4 acc[4];
    #pragma unroll
    for (int mt = 0; mt < 4; ++mt) acc[mt] = (f32x4){0.f, 0.f, 0.f, 0.f};
    for (int kc = 0; kc < 4; ++kc) {
      __syncthreads();
      #pragma unroll
      for (int e = 0; e < 2; ++e) {
        int idx = tid + e * 256;           // 0..511
        int row = idx >> 3, k4 = (idx & 7) * 4;
        float4 v = *reinterpret_cast<const float4*>(&x[((size_t)row * 256 + t) * 128 + kc * 32 + k4]);
        float fv[4] = {v.x, v.y, v.z, v.w};
        bf16x4 a4, b4;
        #pragma unroll
        for (int j = 0; j < 4; ++j) {
          __bf16 a = (__bf16)fv[j];
          a4[j] = a; b4[j] = (__bf16)(fv[j] - (float)a);
        }
        *reinterpret_cast<bf16x4*>(&xs0[row * 36 + k4]) = a4;
        *reinterpret_cast<bf16x4*>(&xs1[row * 36 + k4]) = b4;
        float4 w = *reinterpret_cast<const float4*>(&Vg[(size_t)(cb * 64 + row) * 128 + kc * 32 + k4]);
        float fw[4] = {w.x, w.y, w.z, w.w};
        #pragma unroll
        for (int j = 0; j < 4; ++j) {
          __bf16 a = (__bf16)fw[j];
          a4[j] = a; b4[j] = (__bf16)(fw[j] - (float)a);
        }
        *reinterpret_cast<bf16x4*>(&vs0[row * 36 + k4]) = a4;
        *reinterpret_cast<bf16x4*>(&vs1[row * 36 + k4]) = b4;
      }
      __syncthreads();
      bf16x8 b0 = *reinterpret_cast<const bf16x8*>(&vs0[(wv * 16 + l15) * 36 + q * 8]);
      bf16x8 b1 = *reinterpret_cast<const bf16x8*>(&vs1[(wv * 16 + l15) * 36 + q * 8]);
      #pragma unroll
      for (int mt = 0; mt < 4; ++mt) {
        bf16x8 a0 = *reinterpret_cast<const bf16x8*>(&xs0[(mt * 16 + l15) * 36 + q * 8]);
        bf16x8 a1 = *reinterpret_cast<const bf16x8*>(&xs1[(mt * 16 + l15) * 36 + q * 8]);
        acc[mt] = __builtin_amdgcn_mfma_f32_16x16x32_bf16(a0, b0, acc[mt], 0, 0, 0);
        acc[mt] = __builtin_amdgcn_mfma_f32_16x16x32_bf16(a1, b0, acc[mt], 0, 0, 0);
        acc[mt] = __builtin_amdgcn_mfma_f32_16x16x32_bf16(a0, b1, acc[mt], 0, 0, 0);
      }
    }
    const int col = cb * 64 + wv * 16 + l15;
    const float bv = bias[col];
    #pragma unroll
    for (int mt = 0; mt < 4; ++mt)
      #pragma unroll
      for (int i = 0; i < 4; ++i) {
        int row = mt * 16 + q * 4 + i;
        of[((size_t)t * 64 + row) * 512 + col] = acc[mt][i] + bv;
      }
  }
}

// =========================== K2 mega-kernel =================================
// blocks 0..63: persistent GRU recurrence (R7's measured ~1570us).
// blocks 64..319: e0_xt; 320..351: W1 cast; 352..415: zero grad accumulators.
__global__ __launch_bounds__(256, 1)
void k2_recur(const float* __restrict__ W1w, const float* __restrict__ W2w,
              const float* __restrict__ W3w,
              const float* __restrict__ xv1, const float* __restrict__ xv2,
              const float* __restrict__ xv3,
              __bf16* __restrict__ r_h, __bf16* __restrict__ z_h,
              __bf16* __restrict__ ht_h, __bf16* __restrict__ h_h,
              float* __restrict__ hx, float* __restrict__ hrx,
              int* __restrict__ flags, float* __restrict__ dout,
              const float* __restrict__ x, __bf16* __restrict__ XT,
              __bf16* __restrict__ W1b)
{
  __shared__ __align__(16) char smem[37376];
  const int tid = threadIdx.x;
  const int bid = blockIdx.x;

  if (bid >= 64) {
    if (bid < 320) {
      const int t = bid - 64;
      __bf16* xs = (__bf16*)smem;          // [64][132]
      #pragma unroll
      for (int e = 0; e < 8; ++e) {
        int idx = tid + e * 256;           // 0..2047
        int b = idx >> 5, c4 = (idx & 31) * 4;
        float4 v = *reinterpret_cast<const float4*>(&x[((size_t)b * 256 + t) * 128 + c4]);
        xs[b * 132 + c4 + 0] = (__bf16)v.x; xs[b * 132 + c4 + 1] = (__bf16)v.y;
        xs[b * 132 + c4 + 2] = (__bf16)v.z; xs[b * 132 + c4 + 3] = (__bf16)v.w;
      }
      __syncthreads();
      #pragma unroll
      for (int e = 0; e < 8; ++e) {
        int idx = tid + e * 256;
        int i = idx >> 4, b4 = (idx & 15) * 4;
        __bf16* d = &XT[(size_t)i * TBc + t * 64 + b4];
        d[0] = xs[(b4 + 0) * 132 + i];
        d[1] = xs[(b4 + 1) * 132 + i];
        d[2] = xs[(b4 + 2) * 132 + i];
        d[3] = xs[(b4 + 3) * 132 + i];
      }
    } else if (bid < 352) {
      for (int i = (bid - 320) * 256 + tid; i < 262144; i += 32 * 256)
        W1b[i] = (__bf16)W1w[i];
    } else {
      float* p = dout + O_DW0;
      for (int i = (bid - 352) * 256 + tid; i < 983040; i += 64 * 256)
        p[i] = 0.f;
    }
    return;
  }

  // ---------------- recurrence (identical to R7) ----------------
  const int g  = bid >> 4;
  const int cw = bid & 15;
  const int lane = tid & 63, wv = tid >> 6;
  const int kh = wv & 1;
  const int ct = wv >> 1;
  const int q  = lane >> 4;
  const int colc = cw * 32 + ct * 16 + (lane & 15);
  const bool owner = (kh == 0);

  __bf16* c0  = (__bf16*)smem;
  __bf16* c1  = (__bf16*)(smem + 16384);
  float*  pbuf = (float*)(smem + 32768);

  bf16x8 w1c[2][8], w2c[2][8], w3c[2][8];
  #pragma unroll
  for (int kk2 = 0; kk2 < 8; ++kk2) {
    const int kb = (kh * 8 + kk2) * 32 + q * 8;
    #pragma unroll
    for (int j = 0; j < 8; ++j) {
      float w = W1w[(size_t)colc * 512 + kb + j];
      __bf16 a = (__bf16)w;
      w1c[0][kk2][j] = a; w1c[1][kk2][j] = (__bf16)(w - (float)a);
      w = W2w[(size_t)colc * 512 + kb + j];
      a = (__bf16)w;
      w2c[0][kk2][j] = a; w2c[1][kk2][j] = (__bf16)(w - (float)a);
      w = W3w[(size_t)colc * 512 + kb + j];
      a = (__bf16)w;
      w3c[0][kk2][j] = a; w3c[1][kk2][j] = (__bf16)(w - (float)a);
    }
  }
  for (int i = tid; i < 8192; i += 256) {
    c0[i] = (__bf16)0.f; c1[i] = (__bf16)0.f;
  }
  __syncthreads();

  float hreg[4] = {0.f, 0.f, 0.f, 0.f};
  float* hx_g  = hx  + g * 8192;
  float* hrx_g = hrx + g * 8192;
  int* flags_g = flags + g * 16 * 32;
  const int fragbase = (colc >> 5) * 512 + (((colc >> 3) & 3) * 16 + q * 4) * 8 + (colc & 7);
  const int pb = (ct * 64 + lane) * 9;

  auto stage = [&](const float* __restrict__ srcf) {
    const ull* src = reinterpret_cast<const ull*>(srcf);
    ull u[16];
    #pragma unroll
    for (int j = 0; j < 16; ++j) u[j] = ld64_agent(src + j * 256 + tid);
    #pragma unroll
    for (int j = 0; j < 16; ++j) {
      float f0 = __uint_as_float((unsigned int)u[j]);
      float f1 = __uint_as_float((unsigned int)(u[j] >> 32));
      __bf16 a0 = (__bf16)f0; __bf16 b0 = (__bf16)(f0 - (float)a0);
      __bf16 a1 = (__bf16)f1; __bf16 b1 = (__bf16)(f1 - (float)a1);
      int o = (j * 256 + tid) * 2;
      bf16x2 v0; v0[0] = a0; v0[1] = a1;
      bf16x2 v1; v1[0] = b0; v1[1] = b1;
      *reinterpret_cast<bf16x2*>(&c0[o]) = v0;
      *reinterpret_cast<bf16x2*>(&c1[o]) = v1;
    }
  };

  bool dead = false;
  int bar = 0;
  #pragma unroll 1
  for (int t = 0; t < Tc; ++t) {
    const size_t rowb = ((size_t)t * 64 + g * 16 + q * 4) * 512 + colc;
    float xv1v[4], xv2v[4], xv3v[4];
    if (owner) {
      #pragma unroll
      for (int i = 0; i < 4; ++i) {
        size_t o = rowb + (size_t)i * 512;
        xv1v[i] = xv1[o]; xv2v[i] = xv2[o]; xv3v[i] = xv3[o];
      }
    }
    f32x4 a2 = {0.f,0.f,0.f,0.f}, a3 = {0.f,0.f,0.f,0.f};
    #pragma unroll
    for (int kk2 = 0; kk2 < 8; ++kk2) {
      const int idx = (kh * 8 + kk2) * 512 + lane * 8;
      bf16x8 h0 = *reinterpret_cast<const bf16x8*>(&c0[idx]);
      bf16x8 h1 = *reinterpret_cast<const bf16x8*>(&c1[idx]);
      a2 = __builtin_amdgcn_mfma_f32_16x16x32_bf16(h0, w2c[0][kk2], a2, 0, 0, 0);
      a2 = __builtin_amdgcn_mfma_f32_16x16x32_bf16(h1, w2c[0][kk2], a2, 0, 0, 0);
      a2 = __builtin_amdgcn_mfma_f32_16x16x32_bf16(h0, w2c[1][kk2], a2, 0, 0, 0);
      a3 = __builtin_amdgcn_mfma_f32_16x16x32_bf16(h0, w3c[0][kk2], a3, 0, 0, 0);
      a3 = __builtin_amdgcn_mfma_f32_16x16x32_bf16(h1, w3c[0][kk2], a3, 0, 0, 0);
      a3 = __builtin_amdgcn_mfma_f32_16x16x32_bf16(h0, w3c[1][kk2], a3, 0, 0, 0);
    }
    if (!owner) {
      #pragma unroll
      for (int i = 0; i < 4; ++i) { pbuf[pb + i] = a2[i]; pbuf[pb + 4 + i] = a3[i]; }
    }
    __syncthreads();
    float zz[4], rr4[4];
    if (owner) {
      #pragma unroll
      for (int i = 0; i < 4; ++i) {
        float s2 = a2[i] + pbuf[pb + i]     + xv2v[i];
        float s3 = a3[i] + pbuf[pb + 4 + i] + xv3v[i];
        zz[i]  = 1.f / (1.f + expf(-s2));
        rr4[i] = 1.f / (1.f + expf(-s3));
        st32_agent(&hrx_g[fragbase + i * 8], hreg[i] * rr4[i]);
      }
    }
    ++bar; group_barrier(flags_g, cw, bar, dead);
    if (owner) {
      #pragma unroll
      for (int i = 0; i < 4; ++i) {
        z_h[rowb + (size_t)i * 512] = (__bf16)zz[i];
        r_h[rowb + (size_t)i * 512] = (__bf16)rr4[i];
      }
    }
    stage(hrx_g);
    __syncthreads();
    f32x4 a1 = {0.f,0.f,0.f,0.f};
    #pragma unroll
    for (int kk2 = 0; kk2 < 8; ++kk2) {
      const int idx = (kh * 8 + kk2) * 512 + lane * 8;
      bf16x8 h0 = *reinterpret_cast<const bf16x8*>(&c0[idx]);
      bf16x8 h1 = *reinterpret_cast<const bf16x8*>(&c1[idx]);
      a1 = __builtin_amdgcn_mfma_f32_16x16x32_bf16(h0, w1c[0][kk2], a1, 0, 0, 0);
      a1 = __builtin_amdgcn_mfma_f32_16x16x32_bf16(h1, w1c[0][kk2], a1, 0, 0, 0);
      a1 = __builtin_amdgcn_mfma_f32_16x16x32_bf16(h0, w1c[1][kk2], a1, 0, 0, 0);
    }
    if (!owner) {
      #pragma unroll
      for (int i = 0; i < 4; ++i) pbuf[pb + i] = a1[i];
    }
    __syncthreads();
    float htv[4];
    if (owner) {
      #pragma unroll
      for (int i = 0; i < 4; ++i) {
        float pre = a1[i] + pbuf[pb + i] + xv1v[i];
        float ht = tanhf(pre);
        float hn = zz[i] * (hreg[i] - ht) + ht;
        htv[i] = ht;
        hreg[i] = hn;
        st32_agent(&hx_g[fragbase + i * 8], hn);
      }
    }
    ++bar; group_barrier(flags_g, cw, bar, dead);
    if (owner) {
      #pragma unroll
      for (int i = 0; i < 4; ++i) {
        ht_h[rowb + (size_t)i * 512] = (__bf16)htv[i];
        h_h[rowb + (size_t)i * 512]  = (__bf16)hreg[i];
      }
    }
    if (t + 1 < Tc) stage(hx_g);
    __syncthreads();
  }
  if (owner) {
    #pragma unroll
    for (int i = 0; i < 4; ++i) {
      int b = g * 16 + q * 4 + i;
      dout[O_HT + (size_t)b * 512 + colc] = hreg[i];
    }
  }
}

// =========================== K3M: e1t + k3a merged ==========================
// blocks 0..2047: e1t (HpT/RsHpT transposes); 2048..2063: softmax/error
// (4 batches/block, one wave each). Both depend only on k2 outputs.
// (db1/k_dbzg lives in k5m -- it reads proj, produced by k3b_proj AFTER this.)
__global__ __launch_bounds__(256)
void k3m(const __bf16* __restrict__ r_h, const __bf16* __restrict__ h_h,
         const float* __restrict__ Woutw, const float* __restrict__ Woutb,
         const int* __restrict__ y, float* __restrict__ dout,
         float* __restrict__ errw, __bf16* __restrict__ HpT,
         __bf16* __restrict__ RsHpT)
{
  __shared__ __align__(16) char smem[8704];
  const int bid = blockIdx.x, tid = threadIdx.x;
  if (bid < 2048) {
    // ---- e1t ----
    const int t = bid >> 3, hb = (bid & 7) * 64;
    __bf16* tr = (__bf16*)smem;     // [64][68]
    float hpv[16], rv[16];
    #pragma unroll
    for (int e = 0; e < 16; ++e) {
      int idx = tid + e * 256;
      int b = idx >> 6, hl = idx & 63;
      hpv[e] = hprev_at(h_h, t * 64 + b, hb + hl);
      rv[e]  = (float)r_h[((size_t)t * 64 + b) * 512 + hb + hl];
    }
    for (int rnd = 0; rnd < 2; ++rnd) {
      __syncthreads();
      #pragma unroll
      for (int e = 0; e < 16; ++e) {
        int idx = tid + e * 256;
        int b = idx >> 6, hl = idx & 63;
        tr[b * 68 + hl] = (__bf16)(rnd == 0 ? hpv[e] : rv[e] * hpv[e]);
      }
      __syncthreads();
      __bf16* dst = (rnd == 0) ? HpT : RsHpT;
      #pragma unroll
      for (int e = 0; e < 16; ++e) {
        int idx = tid + e * 256;
        int hl2 = idx >> 6, b2 = idx & 63;
        dst[(size_t)(hb + hl2) * TBc + t * 64 + b2] = tr[b2 * 68 + hl2];
      }
    }
  } else {
    // ---- k3a: softmax/error, one wave per batch row ----
    const int b = (bid - 2048) * 4 + (tid >> 6);
    const int o = tid & 63;
    const float* hrow = dout + O_HT + (size_t)b * 512;
    float sv = Woutb[o];
    for (int k = 0; k < 512; ++k) sv += hrow[k] * Woutw[(size_t)o * 512 + k];
    float mx = sv;
    for (int off = 32; off; off >>= 1) mx = fmaxf(mx, __shfl_xor(mx, off, 64));
    float e = expf(sv - mx);
    float sum = e;
    for (int off = 32; off; off >>= 1) sum += __shfl_xor(sum, off, 64);
    float outp = e / sum;
    float errv = outp - ((y[b] == o) ? 1.f : 0.f);
    dout[O_OUT + b * 64 + o] = outp;
    dout[O_ERR + b * 64 + o] = errv;
    errw[b * 64 + o] = errv;
  }
}

// =========================== K3b: 6 DFA projections ===========================
__global__ __launch_bounds__(256)
void k3b_proj(const float* __restrict__ err,
              const float* b0, const float* b1, const float* b2,
              const float* b3, const float* b4, const float* b5,
              float* __restrict__ proj)
{
  const int p = blockIdx.y;
  const int hb = blockIdx.x * 64;
  const float* BX = (p==0)?b0:(p==1)?b1:(p==2)?b2:(p==3)?b3:(p==4)?b4:b5;
  __shared__ float es[64 * 64];
  __shared__ float bs[64 * 65];
  for (int i = threadIdx.x; i < 4096; i += 256) es[i] = err[i];
  for (int i = threadIdx.x; i < 4096; i += 256) {
    int o = i >> 6, hh = i & 63;
    bs[o * 65 + hh] = BX[(size_t)o * 512 + hb + hh];
  }
  __syncthreads();
  for (int e = 0; e < 16; ++e) {
    int idx = threadIdx.x + e * 256;
    int b = idx >> 6, hh = idx & 63;
    float s = 0.f;
    for (int o = 0; o < 64; ++o) s += es[b * 64 + o] * bs[o * 65 + hh];
    proj[(size_t)p * 32768 + b * 512 + hb + hh] = s;
  }
}

// =========================== K4: plane-pair P GEMM ==========================
// pp=0 -> planes {0:AV,1:AW}; pp=1 -> planes {2:HV,3:HW}. Shared staging &
// epilogue loads -> ~half the memory traffic at identical MFMA count & math.
__global__ __launch_bounds__(256)
void k4_pgemm(const __bf16* __restrict__ z_h, const __bf16* __restrict__ ht_h,
              const __bf16* __restrict__ r_h, const __bf16* __restrict__ h_h,
              const float* __restrict__ proj, const __bf16* __restrict__ W1b,
              __bf16* __restrict__ P)
{
  const int pp = blockIdx.z;
  const int krow0 = blockIdx.x * 128;
  const int n0 = blockIdx.y * 128;
  const float* prA = proj + (size_t)(pp == 0 ? 5 : 1) * 32768;
  const float* prB = proj + (size_t)(pp == 0 ? 4 : 0) * 32768;
  const int tid = threadIdx.x, lane = tid & 63, wv = tid >> 6, q = lane >> 4;
  const int wm = (wv & 1) * 64, wn = (wv >> 1) * 64;
  __shared__ __align__(16) __bf16 Al0[128 * 40];
  __shared__ __align__(16) __bf16 Al1[128 * 40];
  __shared__ __align__(16) __bf16 Bl[128 * 40];
  f32x4 acc0[4][4] = {}, acc1[4][4] = {};
  for (int kt = 0; kt < 16; ++kt) {
    const int h0 = kt * 32;
    __syncthreads();
    #pragma unroll
    for (int e = 0; e < 4; ++e) {
      int idx = tid + e * 256;                 // 0..1023
      int row = idx >> 3, h4 = (idx & 7) * 4;
      int kg = krow0 + row;
      bf16x4 zz = *reinterpret_cast<const bf16x4*>(&z_h[(size_t)kg * 512 + h0 + h4]);
      float4 pva = *reinterpret_cast<const float4*>(&prA[(size_t)(kg & 63) * 512 + h0 + h4]);
      float4 pvb = *reinterpret_cast<const float4*>(&prB[(size_t)(kg & 63) * 512 + h0 + h4]);
      float pA[4] = {pva.x, pva.y, pva.z, pva.w};
      float pB[4] = {pvb.x, pvb.y, pvb.z, pvb.w};
      bf16x4 gv0, gv1;
      if (pp == 0) {
        bf16x4 tt = *reinterpret_cast<const bf16x4*>(&ht_h[(size_t)kg * 512 + h0 + h4]);
        #pragma unroll
        for (int j = 0; j < 4; ++j) {
          float sz = 1.f - (float)zz[j];
          float h = (float)tt[j];
          float f = sz * (1.f - h * h);
          gv0[j] = (__bf16)(pA[j] * f);
          gv1[j] = (__bf16)(pB[j] * f);
        }
      } else {
        #pragma unroll
        for (int j = 0; j < 4; ++j) {
          float sz = 1.f - (float)zz[j];
          gv0[j] = (__bf16)(pA[j] * sz);
          gv1[j] = (__bf16)(pB[j] * sz);
        }
      }
      *reinterpret_cast<bf16x4*>(&Al0[row * 40 + h4]) = gv0;
      *reinterpret_cast<bf16x4*>(&Al1[row * 40 + h4]) = gv1;
      bf16x4 wv4 = *reinterpret_cast<const bf16x4*>(&W1b[(size_t)(n0 + row) * 512 + h0 + h4]);
      *reinterpret_cast<bf16x4*>(&Bl[row * 40 + h4]) = wv4;
    }
    __syncthreads();
    bf16x8 af0[4], af1[4], bfv[4];
    #pragma unroll
    for (int mi = 0; mi < 4; ++mi) {
      af0[mi] = *reinterpret_cast<const bf16x8*>(&Al0[(wm + mi * 16 + (lane & 15)) * 40 + q * 8]);
      af1[mi] = *reinterpret_cast<const bf16x8*>(&Al1[(wm + mi * 16 + (lane & 15)) * 40 + q * 8]);
    }
    #pragma unroll
    for (int ni = 0; ni < 4; ++ni)
      bfv[ni] = *reinterpret_cast<const bf16x8*>(&Bl[(wn + ni * 16 + (lane & 15)) * 40 + q * 8]);
    #pragma unroll
    for (int mi = 0; mi < 4; ++mi)
      #pragma unroll
      for (int ni = 0; ni < 4; ++ni) {
        acc0[mi][ni] = __builtin_amdgcn_mfma_f32_16x16x32_bf16(af0[mi], bfv[ni], acc0[mi][ni], 0, 0, 0);
        acc1[mi][ni] = __builtin_amdgcn_mfma_f32_16x16x32_bf16(af1[mi], bfv[ni], acc1[mi][ni], 0, 0, 0);
      }
  }
  __bf16* Pp0 = P + (size_t)(2 * pp) * THW;
  __bf16* Pp1 = P + (size_t)(2 * pp + 1) * THW;
  #pragma unroll
  for (int mi = 0; mi < 4; ++mi) {
    const int kg = krow0 + wm + mi * 16 + q * 4;
    const int tt = kg >> 6;
    #pragma unroll
    for (int ni = 0; ni < 4; ++ni) {
      const int n = n0 + wn + ni * 16 + (lane & 15);
      union { __bf16 b[4]; uint2 u; } pk0, pk1;
      #pragma unroll
      for (int i = 0; i < 4; ++i) {
        float mul;
        if (pp == 0) {
          float r = (float)r_h[(size_t)(kg + i) * 512 + n];
          float hp = 0.f;
          if (tt != 1) {
            int kr = (tt == 0) ? (16320 + (kg & 63) + i) : (kg + i - 128);
            hp = (float)h_h[(size_t)kr * 512 + n];
          }
          mul = hp * r * (1.f - r);
        } else {
          float h = (float)ht_h[(size_t)(kg + i) * 512 + n];
          mul = 1.f - h * h;
        }
        pk0.b[i] = (__bf16)(acc0[mi][ni][i] * mul);
        pk1.b[i] = (__bf16)(acc1[mi][ni][i] * mul);
      }
      *reinterpret_cast<uint2*>(&Pp0[(size_t)n * TBc + kg]) = pk0.u;
      *reinterpret_cast<uint2*>(&Pp1[(size_t)n * TBc + kg]) = pk1.u;
    }
  }
}

// =========================== K5M: grad GEMMs + dbP + dbzg merged ============
// blocks 0..959: 6 TN grad GEMM jobs; 960..1983: k_dbP column sums (planes
// 2->db0, 0->db2); 1984..2111: k_dbzg db1 partials (reads proj[3], which
// k3b_proj produced before this launch). All inputs ready at launch.
__global__ __launch_bounds__(256)
void k5m(const __bf16* __restrict__ P, const __bf16* __restrict__ RsHpT,
         const __bf16* __restrict__ HpT, const __bf16* __restrict__ XT,
         const __bf16* __restrict__ r_h, const __bf16* __restrict__ ht_h,
         const __bf16* __restrict__ h_h, const float* __restrict__ proj,
         float* __restrict__ dout, float* __restrict__ db, float scale)
{
  __shared__ __align__(16) char smem[36864];
  const int bid = blockIdx.x, tid = threadIdx.x;
  if (bid >= 1984) {
    // ---- k_dbzg: db1 partials ----
    const int b2 = bid - 1984;
    const int hb = (b2 & 7) * 64;
    const int col = hb + (tid & 63);
    const int part = tid >> 6;
    const int kb = (b2 >> 3) * 1024;
    float sum = 0.f;
    for (int k = kb + part; k < kb + 1024; k += 4) {
      float hs = (float)ht_h[(size_t)k * 512 + col];
      float r  = (float)r_h[(size_t)k * 512 + col];
      float hp = hprev_at(h_h, k, col);
      float pv = proj[3 * 32768 + (size_t)(k & 63) * 512 + col];
      sum += (hp - hs) * r * (1.f - r) * pv;
    }
    float (*sred)[64] = (float(*)[64])smem;
    sred[part][tid & 63] = sum;
    __syncthreads();
    if (tid < 64)
      atomicAdd(&db[512 + hb + tid],
                (sred[0][tid] + sred[1][tid] + sred[2][tid] + sred[3][tid]) * (1.f / 64.f));
    return;
  }
  if (bid >= 960) {
    // ---- k_dbP ----
    const int idx = bid - 960;
    const size_t plane = ((idx >> 9) == 0) ? 2 : 0;
    const int dbo = ((idx >> 9) == 0) ? 0 : 1024;
    const int xrow = idx & 511;
    const __bf16* row = P + plane * THW + (size_t)xrow * TBc;
    float sv = 0.f;
    for (int i = tid; i < TBc; i += 256) sv += (float)row[i];
    for (int off = 32; off; off >>= 1) sv += __shfl_xor(sv, off, 64);
    float* red = (float*)smem;
    if ((tid & 63) == 0) red[tid >> 6] = sv;
    __syncthreads();
    if (tid == 0)
      atomicAdd(&db[dbo + xrow], (red[0] + red[1] + red[2] + red[3]) * (1.f / 64.f));
    return;
  }
  const __bf16* Ap; int amode; const __bf16* Bp; const float* projA;
  float* out; int N; int m0i, n0i, zi;
  if (bid < 768) {
    int job = bid >> 8, wb = bid & 255;
    m0i = wb & 3; n0i = (wb >> 2) & 3; zi = wb >> 4;   // zi 0..15
    N = 512;
    out = dout + O_DW0 + (size_t)job * 262144;
    if (job == 0)      { Ap = P + 3 * THW; amode = 0; Bp = RsHpT; projA = proj; }
    else if (job == 1) { Ap = nullptr;     amode = 1; Bp = HpT;   projA = proj + 2 * 32768; }
    else               { Ap = P + 1 * THW; amode = 0; Bp = HpT;   projA = proj; }
  } else {
    int b2 = bid - 768; int job = b2 >> 6, wb = b2 & 63;
    m0i = wb & 3; n0i = 0; zi = wb >> 2;               // zi 0..15
    N = 128;
    out = dout + O_DV0 + (size_t)job * 65536;
    if (job == 0)      { Ap = P + 2 * THW; amode = 0; Bp = XT; projA = proj; }
    else if (job == 1) { Ap = nullptr;     amode = 1; Bp = XT; projA = proj + 3 * 32768; }
    else               { Ap = P + 0 * THW; amode = 0; Bp = XT; projA = proj; }
  }
  const int m0 = m0i * 128;
  const int n0 = n0i * 128;
  const int klen = 1024;
  const int lane = tid & 63, wv = tid >> 6, q = lane >> 4;
  const int wm = (wv & 1) * 64, wn = (wv >> 1) * 64;
  __bf16* Al = (__bf16*)smem;                 // [128][72]
  __bf16* Bl = (__bf16*)(smem + 18432);       // [128][72]
  f32x4 acc[4][4] = {};
  const int iters = klen >> 6;
  for (int kt = 0; kt < iters; ++kt) {
    const int kk0 = zi * klen + kt * 64;
    __syncthreads();
    #pragma unroll
    for (int e = 0; e < 8; ++e) {
      int idx = tid + e * 256;              // 0..2047
      int row = idx >> 4, c4 = (idx & 15) * 4;
      bf16x4 bv = *reinterpret_cast<const bf16x4*>(&Bp[(size_t)(n0 + row) * TBc + kk0 + c4]);
      *reinterpret_cast<bf16x4*>(&Bl[row * 72 + c4]) = bv;
    }
    if (amode == 0) {
      #pragma unroll
      for (int e = 0; e < 8; ++e) {
        int idx = tid + e * 256;
        int row = idx >> 4, c4 = (idx & 15) * 4;
        bf16x4 av = *reinterpret_cast<const bf16x4*>(&Ap[(size_t)(m0 + row) * TBc + kk0 + c4]);
        *reinterpret_cast<bf16x4*>(&Al[row * 72 + c4]) = av;
      }
    } else {
      #pragma unroll
      for (int e = 0; e < 8; ++e) {
        int idx = tid + e * 256;
        int kk = idx >> 5;                  // 0..63 local k row
        int m4 = (idx & 31) * 4;
        int kg = kk0 + kk;
        int tt = kg >> 6;
        bf16x4 hs = *reinterpret_cast<const bf16x4*>(&ht_h[(size_t)kg * 512 + m0 + m4]);
        bf16x4 rv = *reinterpret_cast<const bf16x4*>(&r_h[(size_t)kg * 512 + m0 + m4]);
        float4 pv = *reinterpret_cast<const float4*>(&projA[(size_t)(kg & 63) * 512 + m0 + m4]);
        float pvv[4] = {pv.x, pv.y, pv.z, pv.w};
        float hpf[4] = {0.f, 0.f, 0.f, 0.f};
        if (tt != 1) {
          int kr = (tt == 0) ? (16320 + (kg & 63)) : (kg - 128);
          bf16x4 hp = *reinterpret_cast<const bf16x4*>(&h_h[(size_t)kr * 512 + m0 + m4]);
          #pragma unroll
          for (int j = 0; j < 4; ++j) hpf[j] = (float)hp[j];
        }
        #pragma unroll
        for (int j = 0; j < 4; ++j) {
          float r = (float)rv[j];
          float zg = (hpf[j] - (float)hs[j]) * r * (1.f - r) * pvv[j];
          Al[(m4 + j) * 72 + kk] = (__bf16)zg;
        }
      }
    }
    __syncthreads();
    #pragma unroll
    for (int ks = 0; ks < 2; ++ks) {
      bf16x8 af[4], bfv[4];
      #pragma unroll
      for (int mi = 0; mi < 4; ++mi)
        af[mi] = *reinterpret_cast<const bf16x8*>(&Al[(wm + mi * 16 + (lane & 15)) * 72 + ks * 32 + q * 8]);
      #pragma unroll
      for (int ni = 0; ni < 4; ++ni)
        bfv[ni] = *reinterpret_cast<const bf16x8*>(&Bl[(wn + ni * 16 + (lane & 15)) * 72 + ks * 32 + q * 8]);
      #pragma unroll
      for (int mi = 0; mi < 4; ++mi)
        #pragma unroll
        for (int ni = 0; ni < 4; ++ni)
          acc[mi][ni] = __builtin_amdgcn_mfma_f32_16x16x32_bf16(af[mi], bfv[ni], acc[mi][ni], 0, 0, 0);
    }
  }
  #pragma unroll
  for (int mi = 0; mi < 4; ++mi) {
    const int m = m0 + wm + mi * 16 + q * 4;
    #pragma unroll
    for (int ni = 0; ni < 4; ++ni) {
      const int n = n0 + wn + ni * 16 + (lane & 15);
      #pragma unroll
      for (int i = 0; i < 4; ++i)
        atomicAdd(&out[(size_t)(m + i) * N + n], acc[mi][ni][i] * scale);
    }
  }
}

// =========================== K6: norm + clip (grads live in d_out) ===========================
__global__ void k6a_sumsq(const float* __restrict__ dout, const float* __restrict__ db,
                          float* __restrict__ slots)
{
  const int yy = blockIdx.y;
  const float* src; int count;
  if (yy < 3)      { src = dout + O_DW0 + (size_t)yy * 262144; count = 262144; }
  else if (yy < 6) { src = dout + O_DV0 + (size_t)(yy - 3) * 65536; count = 65536; }
  else             { src = db + (size_t)(yy - 6) * 512; count = 512; }
  int start = blockIdx.x * 4096;
  if (start >= count) return;
  int end = min(start + 4096, count);
  float sp = 0.f;
  for (int i = start + threadIdx.x; i < end; i += 256) { float v = src[i]; sp += v * v; }
  for (int off = 32; off; off >>= 1) sp += __shfl_xor(sp, off, 64);
  __shared__ float red[4];
  if ((threadIdx.x & 63) == 0) red[threadIdx.x >> 6] = sp;
  __syncthreads();
  if (threadIdx.x == 0) atomicAdd(&slots[yy], red[0] + red[1] + red[2] + red[3]);
}

__global__ void k6b_write(const float* __restrict__ db,
                          const float* __restrict__ slots, float* __restrict__ dout)
{
  const int yy = blockIdx.y;
  const float* src; int count; size_t oo;
  if (yy < 3)      { oo = O_DW0 + (size_t)yy * 262144; src = dout + oo; count = 262144; }
  else if (yy < 6) { oo = O_DV0 + (size_t)(yy - 3) * 65536; src = dout + oo; count = 65536; }
  else             { oo = O_DB0 + (size_t)(yy - 6) * 512; src = db + (size_t)(yy - 6) * 512; count = 512; }
  int start = blockIdx.x * 4096;
  if (start >= count) return;
  int end = min(start + 4096, count);
  float inv = 1.f / sqrtf(slots[yy]);
  for (int i = start + threadIdx.x; i < end; i += 256) {
    float v = src[i] * inv;
    dout[oo + i] = fminf(fmaxf(v, -5.f), 5.f);
  }
}

// =========================== launch ===========================
extern "C" void kernel_launch(void* const* d_in, const int* in_sizes, int n_in,
                              void* d_out, int out_size, void* d_ws, size_t ws_size,
                              hipStream_t stream)
{
  const float* x     = (const float*)d_in[0];
  const int*   y     = (const int*)d_in[1];
  const float* W1w   = (const float*)d_in[2];
  const float* V1w   = (const float*)d_in[3];
  const float* V1b   = (const float*)d_in[4];
  const float* W2w   = (const float*)d_in[5];
  const float* W2b   = (const float*)d_in[6];
  const float* V2w   = (const float*)d_in[7];
  const float* W3w   = (const float*)d_in[8];
  const float* W3b   = (const float*)d_in[9];
  const float* V3w   = (const float*)d_in[10];
  const float* Woutw = (const float*)d_in[11];
  const float* Woutb = (const float*)d_in[12];
  const float* BW1   = (const float*)d_in[13];
  const float* BV1   = (const float*)d_in[14];
  const float* BW2   = (const float*)d_in[15];
  const float* BV2   = (const float*)d_in[16];
  const float* BW3   = (const float*)d_in[17];
  const float* BV3   = (const float*)d_in[18];
  float* dout = (float*)d_out;
  char* ws = (char*)d_ws;

  if (ws_size < W_NEED) { ksent<<<1, 1, 0, stream>>>(dout, (float)ws_size); return; }

  float*  slots = (float*)(ws + W_SLOT);
  float*  dbr   = (float*)(ws + W_DB);
  int*    flg   = (int*)(ws + W_FLG);
  float*  errw  = (float*)(ws + W_ERRW);
  float*  proj  = (float*)(ws + W_PROJ);
  __bf16* W1b   = (__bf16*)(ws + W_W1B);
  float*  hx    = (float*)(ws + W_HX);
  float*  hrx   = (float*)(ws + W_HRX);
  __bf16* XT    = (__bf16*)(ws + W_XT);
  __bf16* r_h   = (__bf16*)(ws + W_HIST);
  __bf16* z_h   = (__bf16*)(ws + W_HIST + 16777216);
  __bf16* ht_h  = (__bf16*)(ws + W_HIST + 33554432);
  __bf16* h_h   = (__bf16*)(ws + W_HIST + 50331648);
  char*   PB    = ws + W_PB;

  // xV fp32 (dead after k2) aliases P/HpT/RsHpT (live after k2)
  float* xv1 = (float*)PB;
  float* xv2 = (float*)(PB + 33554432);
  float* xv3 = (float*)(PB + 67108864);
  __bf16* P     = (__bf16*)PB;                     // 4 x [512][TB] bf16 = 67.1 MB
  __bf16* HpT   = (__bf16*)(PB + 67108864);
  __bf16* RsHpT = (__bf16*)(PB + 83886080);

  kzero<<<16, 256, 0, stream>>>((float*)ws, 4096);                  // slots+dbr+flags
  k1_xv<<<dim3(256, 3), 256, 0, stream>>>(x, V1w, V2w, V3w, V1b, W2b, W3b, xv1, xv2, xv3);
  // mega kernel: recurrence (blocks 0..63) + e0_xt (64..319) + W1 cast
  // (320..351) + grad-accumulator zero (352..415) on otherwise-idle CUs
  k2_recur<<<416, 256, 0, stream>>>(W1w, W2w, W3w, xv1, xv2, xv3,
                                    r_h, z_h, ht_h, h_h, hx, hrx, flg, dout,
                                    x, XT, W1b);
  // merged: e1t (0..2047) + k3a (2048..2063)
  k3m<<<2064, 256, 0, stream>>>(r_h, h_h, Woutw, Woutb, y, dout, errw, HpT, RsHpT);
  k3b_proj<<<dim3(8, 6), 256, 0, stream>>>(errw, BW1, BV1, BW2, BV2, BW3, BV3, proj);
  k4_pgemm<<<dim3(128, 4, 2), 256, 0, stream>>>(z_h, ht_h, r_h, h_h, proj, W1b, P);
  const float sc = 1.f / 64.f;
  // merged: dW/dV grad GEMMs klen=1024 (0..959) + k_dbP (960..1983) + k_dbzg (1984..2111)
  k5m<<<2112, 256, 0, stream>>>(P, RsHpT, HpT, XT, r_h, ht_h, h_h, proj, dout, dbr, sc);
  k6a_sumsq<<<dim3(64, 9), 256, 0, stream>>>(dout, dbr, slots);
  k6b_write<<<dim3(64, 9), 256, 0, stream>>>(dbr, slots, dout);
}